// Round 8
// baseline (98.544 us; speedup 1.0000x reference)
//
#include <hip/hip_runtime.h>
#include <hip/hip_bf16.h>

#define Bb 4
#define Ss 2048
#define Dd 512
#define Hh 8
#define HD 64
#define NX (Bb*Ss*Dd)   // 4194304 x elems
#define NW (3*Dd*Dd)    // 786432 weight elems

typedef __attribute__((ext_vector_type(8))) short bf8_t;   // 8 bf16 (4 VGPRs) MFMA operand
typedef __attribute__((ext_vector_type(4))) float f4_t;    // MFMA accumulator
typedef unsigned int u32;
typedef __attribute__((ext_vector_type(4))) unsigned int u32x4;

typedef const unsigned int __attribute__((address_space(1)))* gas_t;
typedef unsigned int __attribute__((address_space(3)))* las_t;

#define LOG2E 1.44269504088896f
#define MBIAS_C (-10000.0f * LOG2E)

__device__ __forceinline__ short cvt1(float f) {           // f32 -> bf16 (native RNE)
  __hip_bfloat16 h = __float2bfloat16(f);
  union { __hip_bfloat16 hh; short ss; } u; u.hh = h; return u.ss;
}

// packed f32x2 -> bf16x2 via COMPILER intrinsic (hazards handled; no bare asm)
__device__ __forceinline__ u32 pkrn(float a, float b) {
  union { __hip_bfloat162 h2; u32 u; } v;
  v.h2 = __float22bfloat162_rn(make_float2(a, b));
  return v.u;
}

__device__ __forceinline__ bf8_t pack8(float4 f0, float4 f1) {
  union { bf8_t v8; u32x4 u4; } u;
  u.u4.x = pkrn(f0.x, f0.y); u.u4.y = pkrn(f0.z, f0.w);
  u.u4.z = pkrn(f1.x, f1.y); u.u4.w = pkrn(f1.z, f1.w);
  return u.v8;
}

__device__ __forceinline__ void gload_lds16(const void* g, void* l) {
  __builtin_amdgcn_global_load_lds((gas_t)g, (las_t)l, 16, 0, 0);
}

// ---------------------------------------------------------------------------
// f32 -> bf16 conversion for x and the three weight matrices.
// ---------------------------------------------------------------------------
__global__ __launch_bounds__(256) void convert_kernel(
    const float* __restrict__ x, const float* __restrict__ Wq,
    const float* __restrict__ Wk, const float* __restrict__ Wv,
    short* __restrict__ xb, short* __restrict__ Wb)
{
  size_t i = ((size_t)blockIdx.x * 256 + threadIdx.x) * 8;
  const float* src; short* dst;
  if (i < (size_t)NX) { src = x + i; dst = xb + i; }
  else {
    size_t j = i - NX;
    int ws = (int)(j >> 18);                 // 262144 elems per W
    const float* W = (ws == 0) ? Wq : (ws == 1) ? Wk : Wv;
    src = W + (j & 0x3FFFF); dst = Wb + j;
  }
  float4 f0 = *(const float4*)src;
  float4 f1 = *(const float4*)(src + 4);
  *(bf8_t*)dst = pack8(f0, f1);
}

// ---------------------------------------------------------------------------
// QKV projection from bf16 x/W. grid (64, 12): 128-row x-tile, 128-col tile
// (= 2 heads); blockIdx.y = proj*4 + col-quarter. 2-phase dbuf via gload_lds.
// Q,K out [b][h][s][hd] (Q pre-scaled by log2e/8); V out [b][h][hd][s].
// ---------------------------------------------------------------------------
__global__ __launch_bounds__(256, 2) void qkv_proj_kernel(
    const short* __restrict__ xb, const short* __restrict__ Wb,
    const float* __restrict__ bq, const float* __restrict__ bk,
    const float* __restrict__ bv,
    short* __restrict__ Qg, short* __restrict__ Kg, short* __restrict__ Vtg)
{
  __shared__ short As[2][128*64];   // 16B-chunk XOR swizzle c^(row&7)
  __shared__ short Bs2[2][128*64];
  const int p = blockIdx.y >> 2;
  const short* __restrict__ W = Wb + (size_t)p * Dd * Dd;
  const float* __restrict__ bias = (p==0) ? bq : (p==1) ? bk : bv;
  const int m0 = blockIdx.x * 128;
  const int n0 = (blockIdx.y & 3) * 128;
  const int tid = threadIdx.x;
  const int lane = tid & 63, wid = tid >> 6;
  const int lq = lane & 15, hi = lane >> 4;
  const int wm = wid & 1, wn = wid >> 1;    // wave -> 64x64 sub-tile

  const short* aSrc[4];
  const short* bSrc[4];
  #pragma unroll
  for (int i = 0; i < 4; i++) {
    int slot = tid + i*256, row = slot >> 3, c = slot & 7;
    aSrc[i] = xb + (size_t)(m0 + row)*Dd + ((c ^ (row&7))*8);
    bSrc[i] = W  + (size_t)(n0 + row)*Dd + ((c ^ (row&7))*8);
  }

  const f4_t zero4 = {0.f, 0.f, 0.f, 0.f};
  f4_t acc[4][4];
  #pragma unroll
  for (int i = 0; i < 4; i++)
    #pragma unroll
    for (int j = 0; j < 4; j++) acc[i][j] = zero4;

  auto STAGE = [&](int bufi, int k0) {
    #pragma unroll
    for (int i = 0; i < 4; i++) {
      gload_lds16(aSrc[i] + k0, &As[bufi][(tid + i*256)*8]);
      gload_lds16(bSrc[i] + k0, &Bs2[bufi][(tid + i*256)*8]);
    }
  };

  STAGE(0, 0);
  __syncthreads();
  for (int kt = 0; kt < 8; kt++) {
    const int cur = kt & 1;
    if (kt < 7) STAGE(cur ^ 1, (kt + 1)*64);
    #pragma unroll
    for (int ks = 0; ks < 2; ks++) {
      const int cu = ks*4 + hi;
      bf8_t a[4], bfrag[4];
      #pragma unroll
      for (int mi = 0; mi < 4; mi++) {
        int row = wm*64 + mi*16 + lq;
        a[mi] = *(const bf8_t*)(&As[cur][row*64 + ((cu ^ (row&7))*8)]);
      }
      #pragma unroll
      for (int nf = 0; nf < 4; nf++) {
        int row = wn*64 + nf*16 + lq;
        bfrag[nf] = *(const bf8_t*)(&Bs2[cur][row*64 + ((cu ^ (row&7))*8)]);
      }
      #pragma unroll
      for (int mi = 0; mi < 4; mi++)
        #pragma unroll
        for (int nf = 0; nf < 4; nf++)
          acc[mi][nf] = __builtin_amdgcn_mfma_f32_16x16x32_bf16(a[mi], bfrag[nf], acc[mi][nf], 0, 0, 0);
    }
    __syncthreads();
  }

  const float qs = (p == 0) ? 0.125f * LOG2E : 1.0f;
  float badd[4];
  #pragma unroll
  for (int nf = 0; nf < 4; nf++) badd[nf] = bias[n0 + wn*64 + nf*16 + lq];
  #pragma unroll
  for (int mi = 0; mi < 4; mi++) {
    #pragma unroll
    for (int nf = 0; nf < 4; nf++) {
      const int col = n0 + wn*64 + nf*16 + lq;     // 0..511
      const int h = col >> 6, hd = col & 63;
      #pragma unroll
      for (int r = 0; r < 4; r++) {
        int mrow = m0 + wm*64 + mi*16 + hi*4 + r;  // C: col=lane&15, row=hi*4+r
        int bb = mrow >> 11, ss = mrow & (Ss-1);
        short val = cvt1((acc[mi][nf][r] + badd[nf]) * qs);
        if (p == 2)
          Vtg[(((size_t)bb*Hh + h)*HD + hd)*Ss + ss] = val;
        else if (p == 0)
          Qg[(((size_t)bb*Hh + h)*Ss + ss)*HD + hd] = val;
        else
          Kg[(((size_t)bb*Hh + h)*Ss + ss)*HD + hd] = val;
      }
    }
  }
}

// ---------------------------------------------------------------------------
// Flash attention fwd. grid (32, 32): blockIdx.x = b*8+h, blockIdx.y = 64-row
// q-tile. 4 waves x 16 q-rows, KV tiles of 64 keys, 2-phase dbuf staging.
// SWAPPED QK^T (mfma(K,Q)): lane holds P^T[key][q=lane&15]; PV A-fragments
// built in-register via v_permlane32_swap + ds_swizzle(lane^16) network
// (no P LDS buffer, no fences, no tr-reads). exp2-domain online softmax with
// scalar per-lane running max + defer-max (THR=11); row-sum via MFMA-ones;
// P pack via __float22bfloat162_rn (compiler intrinsic — round-7 lesson:
// never feed trans-op results into bare inline asm). LDS = 32 KB -> 4 blk/CU.
// ---------------------------------------------------------------------------
__global__ __launch_bounds__(256, 4) void attn_kernel(
    const short* __restrict__ Qg, const short* __restrict__ Kg,
    const short* __restrict__ Vtg, const int* __restrict__ mask,
    float* __restrict__ out)
{
  __shared__ short Ks[2][64*64];   // [key][hd], swizzled
  __shared__ short Vs[2][64*64];   // [hd][key], swizzled
  const int bh = blockIdx.x;
  const int b = bh >> 3, h = bh & 7;
  const int tid = threadIdx.x, lane = tid & 63, w = tid >> 6;
  const int hi = lane >> 4, lq = lane & 15, tau = hi & 1;
  const short* __restrict__ Qb = Qg + (size_t)bh * Ss * HD;
  const short* __restrict__ Kb = Kg + (size_t)bh * Ss * HD;
  const short* __restrict__ Vb = Vtg + (size_t)bh * HD * Ss;
  const int* __restrict__ maskb = mask + b * Ss;
  const int q0 = blockIdx.y * 64 + w * 16;

  // Q fragments (Q already scaled by 0.125*log2e): B-operand, row=lq
  bf8_t qf[2];
  #pragma unroll
  for (int ks = 0; ks < 2; ks++)
    qf[ks] = *(const bf8_t*)(Qb + (size_t)(q0 + lq)*HD + ks*32 + hi*8);

  const f4_t zero4 = {0.f, 0.f, 0.f, 0.f};
  f4_t o[4];
  #pragma unroll
  for (int j = 0; j < 4; j++) o[j] = zero4;
  f4_t lacc = zero4;                        // row-sum accumulator (MFMA-ones)
  float mrun = -1e30f;                      // running max for q = lane&15

  const bf8_t ones = {(short)0x3F80,(short)0x3F80,(short)0x3F80,(short)0x3F80,
                      (short)0x3F80,(short)0x3F80,(short)0x3F80,(short)0x3F80};

  // staging sources: linear LDS dest, swizzle pre-applied on SOURCE (G21)
  const int sA = tid, sB = tid + 256;
  const short* ksrcA = Kb + (size_t)(sA>>3)*HD + (((sA&7) ^ ((sA>>3)&7))*8);
  const short* ksrcB = Kb + (size_t)(sB>>3)*HD + (((sB&7) ^ ((sB>>3)&7))*8);
  const short* vsrcA = Vb + (size_t)(sA>>3)*Ss + (((sA&7) ^ ((sA>>3)&7))*8);
  const short* vsrcB = Vb + (size_t)(sB>>3)*Ss + (((sB&7) ^ ((sB>>3)&7))*8);

  auto STAGE = [&](int bufi, int kv) {
    gload_lds16(ksrcA + (size_t)kv*HD, &Ks[bufi][sA*8]);
    gload_lds16(ksrcB + (size_t)kv*HD, &Ks[bufi][sB*8]);
    gload_lds16(vsrcA + kv,            &Vs[bufi][sA*8]);
    gload_lds16(vsrcB + kv,            &Vs[bufi][sB*8]);
  };

  STAGE(0, 0);
  __syncthreads();
  for (int t = 0; t < Ss/64; t++) {
    const int cur = t & 1;
    if (t + 1 < Ss/64) STAGE(cur ^ 1, (t + 1)*64);
    const int mv = maskb[t*64 + lane];

    // swapped QK^T: sc[kb] = D[k][q], k=kb*16+hi*4+r, q=lq
    f4_t sc[4];
    #pragma unroll
    for (int kb = 0; kb < 4; kb++) {
      const int row = kb*16 + lq;
      bf8_t kf0 = *(const bf8_t*)(&Ks[cur][row*64 + ((hi       ^ (row&7))*8)]);
      bf8_t kf1 = *(const bf8_t*)(&Ks[cur][row*64 + (((4 + hi) ^ (row&7))*8)]);
      sc[kb] = __builtin_amdgcn_mfma_f32_16x16x32_bf16(kf0, qf[0], zero4, 0, 0, 0);
      sc[kb] = __builtin_amdgcn_mfma_f32_16x16x32_bf16(kf1, qf[1], sc[kb], 0, 0, 0);
    }
    if (__any(mv == 0)) {                             // masked keys (rare)
      float mbl = MBIAS_C * (1.0f - (float)mv);
      #pragma unroll
      for (int kb = 0; kb < 4; kb++)
        #pragma unroll
        for (int r = 0; r < 4; r++)
          sc[kb][r] += __shfl(mbl, kb*16 + hi*4 + r, 64);
    }
    // defer-max: local 16-value max vs scalar running max
    float lmax = sc[0][0];
    #pragma unroll
    for (int kb = 0; kb < 4; kb++)
      #pragma unroll
      for (int r = 0; r < 4; r++) lmax = fmaxf(lmax, sc[kb][r]);
    if (__any(lmax > mrun + 11.0f)) {                 // rare: reduce + rescale
      float rmax = fmaxf(lmax, __shfl_xor(lmax, 16, 64));
      rmax = fmaxf(rmax, __shfl_xor(rmax, 32, 64));
      float mnew = fmaxf(mrun, rmax);
      float sf = __builtin_amdgcn_exp2f(mrun - mnew); // first tile: -> 0
      mrun = mnew;
      float sfo[4];
      #pragma unroll
      for (int r = 0; r < 4; r++) sfo[r] = __shfl(sf, hi*4 + r, 64);
      #pragma unroll
      for (int r = 0; r < 4; r++) {
        lacc[r] *= sfo[r];
        #pragma unroll
        for (int nf = 0; nf < 4; nf++) o[nf][r] *= sfo[r];
      }
    }
    // P = exp2(sc - mrun) -> bf16 dword pairs (keys kb*16+hi*4+2d+{0,1})
    u32 Wd[4][2];
    #pragma unroll
    for (int kb = 0; kb < 4; kb++) {
      float p0 = __builtin_amdgcn_exp2f(sc[kb][0] - mrun);
      float p1 = __builtin_amdgcn_exp2f(sc[kb][1] - mrun);
      float p2 = __builtin_amdgcn_exp2f(sc[kb][2] - mrun);
      float p3 = __builtin_amdgcn_exp2f(sc[kb][3] - mrun);
      Wd[kb][0] = pkrn(p0, p1);
      Wd[kb][1] = pkrn(p2, p3);
    }
    // in-register transpose network: dst dword m of pf[c] = keys c*32+hi*8+2m
    bf8_t pf[2];
    #pragma unroll
    for (int c = 0; c < 2; c++) {
      u32 m_[4];
      #pragma unroll
      for (int d = 0; d < 2; d++) {
        u32 X = Wd[2*c][d], Y = Wd[2*c+1][d];
        asm volatile("v_permlane32_swap_b32 %0, %1" : "+v"(X), "+v"(Y));
        u32 Xs = (u32)__builtin_amdgcn_ds_swizzle((int)X, 0x401F); // lane^16
        u32 Ys = (u32)__builtin_amdgcn_ds_swizzle((int)Y, 0x401F);
        m_[d]     = tau ? Ys : X;
        m_[2 + d] = tau ? Y  : Xs;
      }
      union { bf8_t v8; u32x4 u4; } pu;
      pu.u4.x = m_[0]; pu.u4.y = m_[1]; pu.u4.z = m_[2]; pu.u4.w = m_[3];
      pf[c] = pu.v8;
    }
    // MFMA cluster: row-sum + PV
    __builtin_amdgcn_s_setprio(1);
    lacc = __builtin_amdgcn_mfma_f32_16x16x32_bf16(pf[0], ones, lacc, 0, 0, 0);
    lacc = __builtin_amdgcn_mfma_f32_16x16x32_bf16(pf[1], ones, lacc, 0, 0, 0);
    #pragma unroll
    for (int nf2 = 0; nf2 < 4; nf2++) {
      const int vr = nf2*16 + lq;
      #pragma unroll
      for (int ks2 = 0; ks2 < 2; ks2++) {
        bf8_t vf = *(const bf8_t*)(&Vs[cur][vr*64 + (((ks2*4 + hi) ^ (vr&7))*8)]);
        o[nf2] = __builtin_amdgcn_mfma_f32_16x16x32_bf16(pf[ks2], vf, o[nf2], 0, 0, 0);
      }
    }
    __builtin_amdgcn_s_setprio(0);
    __syncthreads();
  }

  // epilogue: normalize and write h[b][s][h*64+hd] (f32)
  #pragma unroll
  for (int nf2 = 0; nf2 < 4; nf2++)
    #pragma unroll
    for (int r = 0; r < 4; r++) {
      int srow = q0 + hi*4 + r;
      out[((size_t)(b*Ss + srow))*Dd + h*HD + nf2*16 + lq] = o[nf2][r] / lacc[r];
    }
}

// ---------------------------------------------------------------------------
extern "C" void kernel_launch(void* const* d_in, const int* in_sizes, int n_in,
                              void* d_out, int out_size, void* d_ws, size_t ws_size,
                              hipStream_t stream) {
  const float* x  = (const float*)d_in[0];
  const int* mask = (const int*)d_in[1];
  const float* Wq = (const float*)d_in[2];
  const float* bq = (const float*)d_in[3];
  const float* Wk = (const float*)d_in[4];
  const float* bk = (const float*)d_in[5];
  const float* Wv = (const float*)d_in[6];
  const float* bv = (const float*)d_in[7];
  float* out = (float*)d_out;

  // ws: Q | K | Vt (each 4.19M shorts) | xb (4.19M) | Wb (786K)  ~= 35 MB
  short* Qg = (short*)d_ws;
  short* Kg = Qg + (size_t)Bb*Hh*Ss*HD;
  short* Vt = Kg + (size_t)Bb*Hh*Ss*HD;
  short* xb = Vt + (size_t)Bb*Hh*Ss*HD;
  short* Wb = xb + (size_t)NX;

  convert_kernel<<<dim3((NX + NW)/2048), 256, 0, stream>>>(x, Wq, Wk, Wv, xb, Wb);
  qkv_proj_kernel<<<dim3(64, 12), 256, 0, stream>>>(xb, Wb, bq, bk, bv, Qg, Kg, Vt);
  attn_kernel<<<dim3(32, 32), 256, 0, stream>>>(Qg, Kg, Vt, mask, out);
}